// Round 5
// baseline (126.795 us; speedup 1.0000x reference)
//
#include <hip/hip_runtime.h>
#include <hip/hip_bf16.h>

// Problem constants (from reference setup_inputs)
#define B_   8
#define T_   4096
#define D_   1024
#define DENT 256
#define F_   1280          // D_ + DENT
#define E_   32            // MAX_EVENTS
#define TVOCAB 512
#define KS   8             // split-K slices
#define KCH  (F_ / KS)     // 160
#define THRB 0x40000000u   // __float_as_uint(2.0f); m>=0 so bit-compare == float-compare

// ---------------------------------------------------------------------------
// Kernel 1: event selection. One block per batch, 1024 threads.
// Keys in registers (4/thread); radix-select (4x8-bit, per-wave private
// histograms); ties -> smallest index (exact lax.top_k). Output sorted by time.
// ---------------------------------------------------------------------------
__global__ __launch_bounds__(1024) void k_select(
    const float* __restrict__ z,
    int* __restrict__ ws_times, int* __restrict__ ws_valid,
    int* __restrict__ ws_cnt,
    float* __restrict__ out_valid, float* __restrict__ out_times)
{
    __shared__ unsigned s_hist[16 * 257];
    __shared__ unsigned s_tot[256];
    __shared__ int s_cnt, s_nsel;
    __shared__ int s_bbin; __shared__ unsigned s_bcg;
    __shared__ int s_selt[E_], s_sorted[E_];
    __shared__ int s_red[16];
    __shared__ int s_prev;

    const int tid  = threadIdx.x;
    const int b    = blockIdx.x;
    const int lane = tid & 63;
    const int wid  = tid >> 6;

    if (b == 0 && tid < 128) ws_cnt[tid] = 0;   // split-K tile counters
    if (tid == 0) { s_cnt = 0; s_nsel = 0; }
    __syncthreads();

    unsigned key[4];
    int cnt = 0;
    const float* zb = z + (size_t)b * T_ * 8;
    #pragma unroll
    for (int j = 0; j < 4; ++j) {
        const int t = tid + j * 1024;
        const float* zp = zb + (size_t)t * 8;
        float4 z0 = *(const float4*)(zp);
        float4 z1 = *(const float4*)(zp + 4);
        float m = fmaxf(fmaxf(fmaxf(fabsf(z0.x), fabsf(z0.y)),
                              fmaxf(fabsf(z0.z), fabsf(z0.w))),
                        fmaxf(fmaxf(fabsf(z1.x), fabsf(z1.y)),
                              fmaxf(fabsf(z1.z), fabsf(z1.w))));
        key[j] = __float_as_uint(m);
        if (key[j] > THRB) cnt++;
    }
    #pragma unroll
    for (int off = 32; off > 0; off >>= 1) cnt += __shfl_down(cnt, off);
    if (lane == 0) atomicAdd(&s_cnt, cnt);
    __syncthreads();

    const int  n_ev = s_cnt;
    const bool fb   = (n_ev < 4);
    const int  V    = fb ? E_ : (n_ev < E_ ? n_ev : E_);

    if (!fb && n_ev <= E_) {
        #pragma unroll
        for (int j = 0; j < 4; ++j)
            if (key[j] > THRB) { int p = atomicAdd(&s_nsel, 1); s_selt[p] = tid + j * 1024; }
        __syncthreads();
    } else {
        unsigned prefix = 0;
        int need = E_;
        for (int p = 0; p < 4; ++p) {
            const int shift = 24 - 8 * p;
            for (int i = tid; i < 16 * 257; i += 1024) s_hist[i] = 0;
            __syncthreads();
            unsigned* h = s_hist + wid * 257;
            #pragma unroll
            for (int j = 0; j < 4; ++j) {
                bool elig = fb || (key[j] > THRB);
                if (elig && (p == 0 || (key[j] >> (shift + 8)) == prefix))
                    atomicAdd(&h[(key[j] >> shift) & 255u], 1u);
            }
            __syncthreads();
            if (tid < 256) {
                unsigned s = 0;
                #pragma unroll
                for (int w = 0; w < 16; ++w) s += s_hist[w * 257 + tid];
                s_tot[tid] = s;
            }
            __syncthreads();
            if (tid < 64) {
                unsigned b0 = s_tot[4*tid+0], b1 = s_tot[4*tid+1];
                unsigned b2 = s_tot[4*tid+2], b3 = s_tot[4*tid+3];
                unsigned lsum = b0 + b1 + b2 + b3;
                unsigned suf = lsum;
                #pragma unroll
                for (int off = 1; off < 64; off <<= 1) {
                    unsigned o = __shfl_down(suf, off);
                    if (tid + off < 64) suf += o;
                }
                unsigned excl = suf - lsum;
                unsigned cg3 = excl;
                unsigned cg2 = cg3 + b3;
                unsigned cg1 = cg2 + b2;
                unsigned cg0 = cg1 + b1;
                unsigned un  = (unsigned)need;
                if (cg3 < un && cg3 + b3 >= un) { s_bbin = 4*tid+3; s_bcg = cg3; }
                if (cg2 < un && cg2 + b2 >= un) { s_bbin = 4*tid+2; s_bcg = cg2; }
                if (cg1 < un && cg1 + b1 >= un) { s_bbin = 4*tid+1; s_bcg = cg1; }
                if (cg0 < un && cg0 + b0 >= un) { s_bbin = 4*tid+0; s_bcg = cg0; }
            }
            __syncthreads();
            need  -= (int)s_bcg;
            prefix = (prefix << 8) | (unsigned)s_bbin;
            __syncthreads();
        }
        const unsigned vstar   = prefix;
        const int      need_eq = need;

        #pragma unroll
        for (int j = 0; j < 4; ++j) {
            bool elig = fb || (key[j] > THRB);
            if (elig && key[j] > vstar) { int p = atomicAdd(&s_nsel, 1); s_selt[p] = tid + j * 1024; }
        }
        __syncthreads();
        int prev = -1;
        const int base = s_nsel;
        for (int q = 0; q < need_eq; ++q) {
            int best = 0x7fffffff;
            #pragma unroll
            for (int j = 0; j < 4; ++j) {
                bool elig = fb || (key[j] > THRB);
                int  t    = tid + j * 1024;
                if (elig && key[j] == vstar && t > prev && t < best) best = t;
            }
            #pragma unroll
            for (int off = 32; off > 0; off >>= 1) {
                int o = __shfl_down(best, off);
                if (o < best) best = o;
            }
            if (lane == 0) s_red[wid] = best;
            __syncthreads();
            if (tid == 0) {
                int m = s_red[0];
                #pragma unroll
                for (int w = 1; w < 16; ++w) if (s_red[w] < m) m = s_red[w];
                s_selt[base + q] = m;
                s_prev = m;
            }
            __syncthreads();
            prev = s_prev;
        }
    }

    if (tid < V) {
        int ti = s_selt[tid];
        int rank = 0;
        for (int j = 0; j < V; ++j) rank += (s_selt[j] < ti);
        s_sorted[rank] = ti;
    }
    __syncthreads();
    if (tid < E_) {
        int valid = (tid < V) ? 1 : 0;
        int t     = valid ? s_sorted[tid] : 0;
        ws_times[b * E_ + tid]  = t;
        ws_valid[b * E_ + tid]  = valid;
        out_times[b * E_ + tid] = (float)t;
        out_valid[b * E_ + tid] = (float)valid;
    }
}

// ---------------------------------------------------------------------------
// Kernel 2: split-K GEMM, occupancy-driven: 1024 blocks (4/CU, 4 waves/SIMD).
// Tile 32x64, KS=8 (KCH=160 = 5 x BK=32). LDS double-buffer + explicit
// register pipeline on the ff-loop. Deterministic completion-counter reduce.
// ---------------------------------------------------------------------------
#define BM 32
#define BN 64
#define BK 32
#define SA (BM + 2)   // 34: A write pattern 2-way (free), float2 read aligned
#define SB (BN + 4)   // 68: keeps float4 LDS reads 16B-aligned

__global__ __launch_bounds__(256, 4) void k_gemm_fused(
    const float* __restrict__ h_seq, const float* __restrict__ ent,
    const float* __restrict__ W, const float* __restrict__ bias,
    const float* __restrict__ temb,
    const int* __restrict__ ws_times, const int* __restrict__ ws_valid,
    int* __restrict__ ws_cnt, float* __restrict__ part,
    float* __restrict__ out)
{
    __shared__ float As[2][BK][SA];
    __shared__ float Bs[2][BK][SB];
    __shared__ int s_old;

    const int tid = threadIdx.x;
    // XCD-aware swizzle: 2 col-panels per XCD; (row,ks) siblings co-located.
    const int bflat = blockIdx.x;          // 0..1023
    const int xcd   = bflat & 7;
    const int j     = bflat >> 3;          // 0..127
    const int yc    = xcd * 2 + (j >> 6);  // col tile 0..15
    const int rk    = j & 63;
    const int xr    = rk & 7;              // row tile 0..7
    const int zs    = rk >> 3;             // k slice 0..7

    const int row0 = xr * BM;
    const int col0 = yc * BN;
    const int f0   = zs * KCH;
    const int tile = xr * 16 + yc;         // 0..127

    // ---- loader setup: A = 1 float4/thread, B = 2 float4/thread ----
    const int rA = tid >> 3;               // 0..31
    const int fA = (tid & 7) * 4;          // 0..28
    size_t a_baseh, a_basee;
    float  a_v;
    {
        int grow = row0 + rA;
        int t    = ws_times[grow];
        a_v      = (float)ws_valid[grow];
        int bb   = grow >> 5;
        a_baseh  = ((size_t)bb * T_ + t) * D_   + fA;
        a_basee  = ((size_t)bb * T_ + t) * DENT + fA;
    }
    int    rB[2]; size_t b_base[2];
    #pragma unroll
    for (int i = 0; i < 2; ++i) {
        int idx = tid + i * 256;
        rB[i] = idx >> 3;                  // 0..63
        b_base[i] = (size_t)(col0 + rB[i]) * F_ + (idx & 7) * 4;
    }

    const int tr = tid >> 4;   // 0..15 -> rows tr*2..tr*2+1
    const int tc = tid & 15;   // 0..15 -> cols tc*4..tc*4+3

    float4 ra, rb0, rb1;
    float acc[2][4] = {};

#define LOAD_TILE(KC) do {                                                   \
    int fbase = f0 + (KC) * BK;                                              \
    if (fbase < D_) ra = *(const float4*)(h_seq + a_baseh + fbase);          \
    else            ra = *(const float4*)(ent + a_basee + (fbase - D_));     \
    rb0 = *(const float4*)(W + b_base[0] + fbase);                           \
    rb1 = *(const float4*)(W + b_base[1] + fbase);                           \
} while (0)

#define STORE_TILE(BUF) do {                                                 \
    As[BUF][fA + 0][rA] = ra.x * a_v;                                        \
    As[BUF][fA + 1][rA] = ra.y * a_v;                                        \
    As[BUF][fA + 2][rA] = ra.z * a_v;                                        \
    As[BUF][fA + 3][rA] = ra.w * a_v;                                        \
    Bs[BUF][fA + 0][rB[0]] = rb0.x;                                          \
    Bs[BUF][fA + 1][rB[0]] = rb0.y;                                          \
    Bs[BUF][fA + 2][rB[0]] = rb0.z;                                          \
    Bs[BUF][fA + 3][rB[0]] = rb0.w;                                          \
    Bs[BUF][fA + 0][rB[1]] = rb1.x;                                          \
    Bs[BUF][fA + 1][rB[1]] = rb1.y;                                          \
    Bs[BUF][fA + 2][rB[1]] = rb1.z;                                          \
    Bs[BUF][fA + 3][rB[1]] = rb1.w;                                          \
} while (0)

    LOAD_TILE(0);
    STORE_TILE(0);
    __syncthreads();

    const int NIT = KCH / BK;   // 5
    for (int kc = 0; kc < NIT; ++kc) {
        const int cur = kc & 1;
        if (kc < NIT - 1) LOAD_TILE(kc + 1);

        // ff-loop with explicit 1-deep register pipeline
        float2 a_c = *(const float2*)&As[cur][0][tr * 2];
        float4 b_c = *(const float4*)&Bs[cur][0][tc * 4];
        #pragma unroll
        for (int ff = 0; ff < BK; ++ff) {
            float2 a_n; float4 b_n;
            if (ff < BK - 1) {
                a_n = *(const float2*)&As[cur][ff + 1][tr * 2];
                b_n = *(const float4*)&Bs[cur][ff + 1][tc * 4];
            }
            acc[0][0] = fmaf(a_c.x, b_c.x, acc[0][0]);
            acc[0][1] = fmaf(a_c.x, b_c.y, acc[0][1]);
            acc[0][2] = fmaf(a_c.x, b_c.z, acc[0][2]);
            acc[0][3] = fmaf(a_c.x, b_c.w, acc[0][3]);
            acc[1][0] = fmaf(a_c.y, b_c.x, acc[1][0]);
            acc[1][1] = fmaf(a_c.y, b_c.y, acc[1][1]);
            acc[1][2] = fmaf(a_c.y, b_c.z, acc[1][2]);
            acc[1][3] = fmaf(a_c.y, b_c.w, acc[1][3]);
            a_c = a_n; b_c = b_n;
        }

        if (kc < NIT - 1) { STORE_TILE(cur ^ 1); __syncthreads(); }
    }
#undef LOAD_TILE
#undef STORE_TILE

    // ---- write partial slice ----
    float* pout = part + (size_t)zs * (B_ * E_ * D_);
    #pragma unroll
    for (int j2 = 0; j2 < 2; ++j2) {
        int grow = row0 + tr * 2 + j2;
        *(float4*)(pout + (size_t)grow * D_ + col0 + tc * 4) =
            make_float4(acc[j2][0], acc[j2][1], acc[j2][2], acc[j2][3]);
    }

    // ---- completion counter; last block per tile reduces (fixed k order) ----
    __threadfence();
    __syncthreads();
    if (tid == 0) s_old = atomicAdd(&ws_cnt[tile], 1);
    __syncthreads();
    if (s_old == KS - 1) {
        __threadfence();
        const int cbase = col0 + tc * 4;
        const float4 bi = *(const float4*)(bias + cbase);
        #pragma unroll
        for (int j2 = 0; j2 < 2; ++j2) {
            int grow = row0 + tr * 2 + j2;
            float4 s = make_float4(0.f, 0.f, 0.f, 0.f);
            #pragma unroll
            for (int k = 0; k < KS; ++k) {
                const float4 pv = *(const float4*)(part
                    + (size_t)k * (B_ * E_ * D_) + (size_t)grow * D_ + cbase);
                s.x += pv.x; s.y += pv.y; s.z += pv.z; s.w += pv.w;
            }
            int t  = ws_times[grow];
            int tcl = t < (TVOCAB - 1) ? t : (TVOCAB - 1);
            const float4 te = *(const float4*)(temb + (size_t)tcl * D_ + cbase);
            s.x += bi.x + te.x; s.y += bi.y + te.y;
            s.z += bi.z + te.z; s.w += bi.w + te.w;
            *(float4*)(out + (size_t)grow * D_ + cbase) = s;
        }
    }
}

// ---------------------------------------------------------------------------
// Fallback single-kernel GEMM (if ws too small) — known-good round-1 code.
// ---------------------------------------------------------------------------
#define FBM 64
#define FBN 64
#define FPAD 4

__global__ __launch_bounds__(256) void k_gemm_full(
    const float* __restrict__ h_seq, const float* __restrict__ ent,
    const float* __restrict__ W, const float* __restrict__ bias,
    const float* __restrict__ temb,
    const int* __restrict__ ws_times, const int* __restrict__ ws_valid,
    float* __restrict__ out)
{
    __shared__ float As[BK][FBM + FPAD];
    __shared__ float Bs[BK][FBN + FPAD];

    const int tid  = threadIdx.x;
    const int row0 = blockIdx.x * FBM;
    const int col0 = blockIdx.y * FBN;

    size_t a_baseh[2], a_basee[2], b_base[2];
    float  a_v[2];
    int    l_row[2], l_f4[2];
    #pragma unroll
    for (int i = 0; i < 2; ++i) {
        int idx = tid + i * 256;
        int row = idx >> 3, f4 = idx & 7;
        l_row[i] = row; l_f4[i] = f4;
        int grow = row0 + row;
        int t    = ws_times[grow];
        a_v[i]   = (float)ws_valid[grow];
        int bb   = grow >> 5;
        a_baseh[i] = ((size_t)bb * T_ + t) * D_   + f4 * 4;
        a_basee[i] = ((size_t)bb * T_ + t) * DENT + f4 * 4;
        b_base[i]  = (size_t)(col0 + row) * F_ + f4 * 4;
    }

    const int rg = tid >> 4;
    const int cg = tid & 15;
    float acc[4][4] = {};

    for (int kc = 0; kc < F_ / BK; ++kc) {
        const int fbase = kc * BK;
        #pragma unroll
        for (int i = 0; i < 2; ++i) {
            float4 val;
            if (fbase < D_) val = *(const float4*)(h_seq + a_baseh[i] + fbase);
            else            val = *(const float4*)(ent + a_basee[i] + (fbase - D_));
            float v = a_v[i];
            int f = l_f4[i] * 4, r = l_row[i];
            As[f + 0][r] = val.x * v;
            As[f + 1][r] = val.y * v;
            As[f + 2][r] = val.z * v;
            As[f + 3][r] = val.w * v;
            float4 wv = *(const float4*)(W + b_base[i] + fbase);
            Bs[f + 0][r] = wv.x;
            Bs[f + 1][r] = wv.y;
            Bs[f + 2][r] = wv.z;
            Bs[f + 3][r] = wv.w;
        }
        __syncthreads();
        #pragma unroll
        for (int ff = 0; ff < BK; ++ff) {
            const float4 av = *(const float4*)&As[ff][rg * 4];
            const float4 bv = *(const float4*)&Bs[ff][cg * 4];
            #pragma unroll
            for (int j = 0; j < 4; ++j) {
                float a = (&av.x)[j];
                acc[j][0] = fmaf(a, bv.x, acc[j][0]);
                acc[j][1] = fmaf(a, bv.y, acc[j][1]);
                acc[j][2] = fmaf(a, bv.z, acc[j][2]);
                acc[j][3] = fmaf(a, bv.w, acc[j][3]);
            }
        }
        __syncthreads();
    }

    const int cbase = col0 + cg * 4;
    const float4 bi = *(const float4*)(bias + cbase);
    #pragma unroll
    for (int j = 0; j < 4; ++j) {
        int grow = row0 + rg * 4 + j;
        int t    = ws_times[grow];
        int tc   = t < (TVOCAB - 1) ? t : (TVOCAB - 1);
        const float4 te = *(const float4*)(temb + (size_t)tc * D_ + cbase);
        float4 o;
        o.x = acc[j][0] + bi.x + te.x;
        o.y = acc[j][1] + bi.y + te.y;
        o.z = acc[j][2] + bi.z + te.z;
        o.w = acc[j][3] + bi.w + te.w;
        *(float4*)(out + (size_t)grow * D_ + cbase) = o;
    }
}

// ---------------------------------------------------------------------------
extern "C" void kernel_launch(void* const* d_in, const int* in_sizes, int n_in,
                              void* d_out, int out_size, void* d_ws, size_t ws_size,
                              hipStream_t stream)
{
    const float* h_seq = (const float*)d_in[0];
    const float* z     = (const float*)d_in[1];
    const float* ent   = (const float*)d_in[2];
    const float* W     = (const float*)d_in[3];
    const float* bias  = (const float*)d_in[4];
    const float* temb  = (const float*)d_in[5];

    float* out       = (float*)d_out;
    float* out_tape  = out;                                // 262144
    float* out_valid = out + (size_t)B_ * E_ * D_;         // 256
    float* out_times = out_valid + B_ * E_;                // 256

    // ws layout: [0] times (256 int) | [1KB] valid (256 int)
    //            [2KB] tile counters (128 int) | [4KB] partials (8 MB)
    int*   ws_times = (int*)d_ws;
    int*   ws_valid = (int*)((char*)d_ws + 1024);
    int*   ws_cnt   = (int*)((char*)d_ws + 2048);
    float* part     = (float*)((char*)d_ws + 4096);

    k_select<<<B_, 1024, 0, stream>>>(z, ws_times, ws_valid, ws_cnt,
                                      out_valid, out_times);

    const size_t need = 4096 + (size_t)KS * B_ * E_ * D_ * sizeof(float);
    if (ws_size >= need) {
        k_gemm_fused<<<1024, 256, 0, stream>>>(h_seq, ent, W, bias, temb,
                                               ws_times, ws_valid, ws_cnt,
                                               part, out_tape);
    } else {
        dim3 g2((B_ * E_) / FBM, D_ / FBN);
        k_gemm_full<<<g2, 256, 0, stream>>>(h_seq, ent, W, bias, temb,
                                            ws_times, ws_valid, out_tape);
    }
}

// Round 6
// 44.590 us; speedup vs baseline: 2.8436x; 2.8436x over previous
//
#include <hip/hip_runtime.h>
#include <hip/hip_bf16.h>

// Problem constants (from reference setup_inputs)
#define B_   8
#define T_   4096
#define D_   1024
#define DENT 256
#define F_   1280          // D_ + DENT
#define E_   32            // MAX_EVENTS
#define TVOCAB 512
#define THRB 0x40000000u   // __float_as_uint(2.0f); m>=0 so bit-compare == float-compare

// ---------------------------------------------------------------------------
// Kernel 1: event selection. One block per batch, 1024 threads.
// Keys in registers (4/thread); radix-select (4x8-bit, per-wave private
// histograms); ties -> smallest index (exact lax.top_k). Output sorted by time.
// (proven ~4us in rounds 4/5; unchanged except ws_cnt removal)
// ---------------------------------------------------------------------------
__global__ __launch_bounds__(1024) void k_select(
    const float* __restrict__ z,
    int* __restrict__ ws_times, int* __restrict__ ws_valid,
    float* __restrict__ out_valid, float* __restrict__ out_times)
{
    __shared__ unsigned s_hist[16 * 257];
    __shared__ unsigned s_tot[256];
    __shared__ int s_cnt, s_nsel;
    __shared__ int s_bbin; __shared__ unsigned s_bcg;
    __shared__ int s_selt[E_], s_sorted[E_];
    __shared__ int s_red[16];
    __shared__ int s_prev;

    const int tid  = threadIdx.x;
    const int b    = blockIdx.x;
    const int lane = tid & 63;
    const int wid  = tid >> 6;

    if (tid == 0) { s_cnt = 0; s_nsel = 0; }
    __syncthreads();

    unsigned key[4];
    int cnt = 0;
    const float* zb = z + (size_t)b * T_ * 8;
    #pragma unroll
    for (int j = 0; j < 4; ++j) {
        const int t = tid + j * 1024;
        const float* zp = zb + (size_t)t * 8;
        float4 z0 = *(const float4*)(zp);
        float4 z1 = *(const float4*)(zp + 4);
        float m = fmaxf(fmaxf(fmaxf(fabsf(z0.x), fabsf(z0.y)),
                              fmaxf(fabsf(z0.z), fabsf(z0.w))),
                        fmaxf(fmaxf(fabsf(z1.x), fabsf(z1.y)),
                              fmaxf(fabsf(z1.z), fabsf(z1.w))));
        key[j] = __float_as_uint(m);
        if (key[j] > THRB) cnt++;
    }
    #pragma unroll
    for (int off = 32; off > 0; off >>= 1) cnt += __shfl_down(cnt, off);
    if (lane == 0) atomicAdd(&s_cnt, cnt);
    __syncthreads();

    const int  n_ev = s_cnt;
    const bool fb   = (n_ev < 4);
    const int  V    = fb ? E_ : (n_ev < E_ ? n_ev : E_);

    if (!fb && n_ev <= E_) {
        #pragma unroll
        for (int j = 0; j < 4; ++j)
            if (key[j] > THRB) { int p = atomicAdd(&s_nsel, 1); s_selt[p] = tid + j * 1024; }
        __syncthreads();
    } else {
        unsigned prefix = 0;
        int need = E_;
        for (int p = 0; p < 4; ++p) {
            const int shift = 24 - 8 * p;
            for (int i = tid; i < 16 * 257; i += 1024) s_hist[i] = 0;
            __syncthreads();
            unsigned* h = s_hist + wid * 257;
            #pragma unroll
            for (int j = 0; j < 4; ++j) {
                bool elig = fb || (key[j] > THRB);
                if (elig && (p == 0 || (key[j] >> (shift + 8)) == prefix))
                    atomicAdd(&h[(key[j] >> shift) & 255u], 1u);
            }
            __syncthreads();
            if (tid < 256) {
                unsigned s = 0;
                #pragma unroll
                for (int w = 0; w < 16; ++w) s += s_hist[w * 257 + tid];
                s_tot[tid] = s;
            }
            __syncthreads();
            if (tid < 64) {
                unsigned b0 = s_tot[4*tid+0], b1 = s_tot[4*tid+1];
                unsigned b2 = s_tot[4*tid+2], b3 = s_tot[4*tid+3];
                unsigned lsum = b0 + b1 + b2 + b3;
                unsigned suf = lsum;
                #pragma unroll
                for (int off = 1; off < 64; off <<= 1) {
                    unsigned o = __shfl_down(suf, off);
                    if (tid + off < 64) suf += o;
                }
                unsigned excl = suf - lsum;
                unsigned cg3 = excl;
                unsigned cg2 = cg3 + b3;
                unsigned cg1 = cg2 + b2;
                unsigned cg0 = cg1 + b1;
                unsigned un  = (unsigned)need;
                if (cg3 < un && cg3 + b3 >= un) { s_bbin = 4*tid+3; s_bcg = cg3; }
                if (cg2 < un && cg2 + b2 >= un) { s_bbin = 4*tid+2; s_bcg = cg2; }
                if (cg1 < un && cg1 + b1 >= un) { s_bbin = 4*tid+1; s_bcg = cg1; }
                if (cg0 < un && cg0 + b0 >= un) { s_bbin = 4*tid+0; s_bcg = cg0; }
            }
            __syncthreads();
            need  -= (int)s_bcg;
            prefix = (prefix << 8) | (unsigned)s_bbin;
            __syncthreads();
        }
        const unsigned vstar   = prefix;
        const int      need_eq = need;

        #pragma unroll
        for (int j = 0; j < 4; ++j) {
            bool elig = fb || (key[j] > THRB);
            if (elig && key[j] > vstar) { int p = atomicAdd(&s_nsel, 1); s_selt[p] = tid + j * 1024; }
        }
        __syncthreads();
        int prev = -1;
        const int base = s_nsel;
        for (int q = 0; q < need_eq; ++q) {
            int best = 0x7fffffff;
            #pragma unroll
            for (int j = 0; j < 4; ++j) {
                bool elig = fb || (key[j] > THRB);
                int  t    = tid + j * 1024;
                if (elig && key[j] == vstar && t > prev && t < best) best = t;
            }
            #pragma unroll
            for (int off = 32; off > 0; off >>= 1) {
                int o = __shfl_down(best, off);
                if (o < best) best = o;
            }
            if (lane == 0) s_red[wid] = best;
            __syncthreads();
            if (tid == 0) {
                int m = s_red[0];
                #pragma unroll
                for (int w = 1; w < 16; ++w) if (s_red[w] < m) m = s_red[w];
                s_selt[base + q] = m;
                s_prev = m;
            }
            __syncthreads();
            prev = s_prev;
        }
    }

    if (tid < V) {
        int ti = s_selt[tid];
        int rank = 0;
        for (int j = 0; j < V; ++j) rank += (s_selt[j] < ti);
        s_sorted[rank] = ti;
    }
    __syncthreads();
    if (tid < E_) {
        int valid = (tid < V) ? 1 : 0;
        int t     = valid ? s_sorted[tid] : 0;
        ws_times[b * E_ + tid]  = t;
        ws_valid[b * E_ + tid]  = valid;
        out_times[b * E_ + tid] = (float)t;
        out_valid[b * E_ + tid] = (float)valid;
    }
}

// ---------------------------------------------------------------------------
// Kernel 2: single-kernel GEMM, latency-amortized.
// Grid 256 blocks (8 row-tiles x 32 col-tiles), tile 32x32, FULL K=1280 as
// 10 iters of BK=128. No split-K, no fences, no partials.
// Per iter: per-wave compute ~2.5K cyc >> HBM latency; next-tile global
// loads are issued into registers BEFORE the compute phase.
// LDS row-major [32][132] (pad keeps f4 16B-aligned); microtile rows
// {tr,tr+16} x cols {tc,tc+16} -> 2-way bank aliasing (free).
// ---------------------------------------------------------------------------
#define BK   128
#define LDP  132           // row pitch in floats (132*4 % 16 == 0)
#define NIT  (F_ / BK)     // 10

__global__ __launch_bounds__(256, 4) void k_gemm(
    const float* __restrict__ h_seq, const float* __restrict__ ent,
    const float* __restrict__ W, const float* __restrict__ bias,
    const float* __restrict__ temb,
    const int* __restrict__ ws_times, const int* __restrict__ ws_valid,
    float* __restrict__ out)
{
    __shared__ float As[32][LDP];
    __shared__ float Bs[32][LDP];

    const int tid = threadIdx.x;
    // XCD-aware swizzle: XCD k gets col-tiles [4k..4k+3] x all row-tiles.
    // Per-XCD footprint: W panel 640KB + A 1.25MB -> L2-resident.
    const int flat  = blockIdx.x;          // 0..255
    const int xcd   = flat & 7;
    const int i     = flat >> 3;           // 0..31
    const int combo = xcd * 32 + i;        // 0..255
    const int yc    = combo >> 3;          // col tile 0..31
    const int xr    = combo & 7;           // row tile 0..7

    const int row0 = xr * 32;
    const int col0 = yc * 32;

    // ---- loader setup: each thread loads 4 float4 for A and 4 for B ----
    const int lrow = tid >> 3;             // 0..31 (A row / B col within tile)
    const int lfo  = (tid & 7) * 4;        // float offset 0..28 within 32-float chunk
    size_t a_baseh, a_basee, b_base;
    float  a_v;
    {
        int grow = row0 + lrow;
        int t    = ws_times[grow];
        a_v      = (float)ws_valid[grow];
        int bb   = grow >> 5;
        a_baseh  = ((size_t)bb * T_ + t) * D_   + lfo;
        a_basee  = ((size_t)bb * T_ + t) * DENT + lfo;
        b_base   = (size_t)(col0 + lrow) * F_ + lfo;
    }

    const int tr = tid >> 4;   // 0..15 -> rows {tr, tr+16}
    const int tc = tid & 15;   // 0..15 -> cols {tc, tc+16}

    float4 ra[4], rb[4];
    float acc00 = 0.f, acc01 = 0.f, acc10 = 0.f, acc11 = 0.f;

#define LOAD_TILE(KC) do {                                                   \
    const int fb0 = (KC) * BK;                                               \
    const float* asrc; size_t abase;                                         \
    if (fb0 < D_) { asrc = h_seq; abase = a_baseh + fb0; }                   \
    else          { asrc = ent;   abase = a_basee + (fb0 - D_); }            \
    _Pragma("unroll")                                                        \
    for (int j = 0; j < 4; ++j) {                                            \
        ra[j] = *(const float4*)(asrc + abase + j * 32);                     \
        rb[j] = *(const float4*)(W + b_base + fb0 + j * 32);                 \
    } } while (0)

    LOAD_TILE(0);

    for (int kc = 0; kc < NIT; ++kc) {
        __syncthreads();   // LDS free (previous compute done)
        #pragma unroll
        for (int j = 0; j < 4; ++j) {
            float4 av = ra[j];
            av.x *= a_v; av.y *= a_v; av.z *= a_v; av.w *= a_v;
            *(float4*)&As[lrow][lfo + j * 32] = av;
            *(float4*)&Bs[lrow][lfo + j * 32] = rb[j];
        }
        __syncthreads();

        if (kc < NIT - 1) LOAD_TILE(kc + 1);   // issue next tile NOW

        #pragma unroll
        for (int g = 0; g < BK / 4; ++g) {
            const float4 a0 = *(const float4*)&As[tr     ][g * 4];
            const float4 a1 = *(const float4*)&As[tr + 16][g * 4];
            const float4 b0 = *(const float4*)&Bs[tc     ][g * 4];
            const float4 b1 = *(const float4*)&Bs[tc + 16][g * 4];
            acc00 = fmaf(a0.x, b0.x, acc00); acc00 = fmaf(a0.y, b0.y, acc00);
            acc00 = fmaf(a0.z, b0.z, acc00); acc00 = fmaf(a0.w, b0.w, acc00);
            acc01 = fmaf(a0.x, b1.x, acc01); acc01 = fmaf(a0.y, b1.y, acc01);
            acc01 = fmaf(a0.z, b1.z, acc01); acc01 = fmaf(a0.w, b1.w, acc01);
            acc10 = fmaf(a1.x, b0.x, acc10); acc10 = fmaf(a1.y, b0.y, acc10);
            acc10 = fmaf(a1.z, b0.z, acc10); acc10 = fmaf(a1.w, b0.w, acc10);
            acc11 = fmaf(a1.x, b1.x, acc11); acc11 = fmaf(a1.y, b1.y, acc11);
            acc11 = fmaf(a1.z, b1.z, acc11); acc11 = fmaf(a1.w, b1.w, acc11);
        }
    }
#undef LOAD_TILE

    // ---- epilogue: + bias + time_embed[clip(t)] ----
    const int c0 = col0 + tc;
    const int c1 = col0 + tc + 16;
    const float bi0 = bias[c0], bi1 = bias[c1];
    {
        int grow = row0 + tr;
        int t    = ws_times[grow];
        int tcl  = t < (TVOCAB - 1) ? t : (TVOCAB - 1);
        const float* te = temb + (size_t)tcl * D_;
        out[(size_t)grow * D_ + c0] = acc00 + bi0 + te[c0];
        out[(size_t)grow * D_ + c1] = acc01 + bi1 + te[c1];
    }
    {
        int grow = row0 + tr + 16;
        int t    = ws_times[grow];
        int tcl  = t < (TVOCAB - 1) ? t : (TVOCAB - 1);
        const float* te = temb + (size_t)tcl * D_;
        out[(size_t)grow * D_ + c0] = acc10 + bi0 + te[c0];
        out[(size_t)grow * D_ + c1] = acc11 + bi1 + te[c1];
    }
}

// ---------------------------------------------------------------------------
extern "C" void kernel_launch(void* const* d_in, const int* in_sizes, int n_in,
                              void* d_out, int out_size, void* d_ws, size_t ws_size,
                              hipStream_t stream)
{
    const float* h_seq = (const float*)d_in[0];
    const float* z     = (const float*)d_in[1];
    const float* ent   = (const float*)d_in[2];
    const float* W     = (const float*)d_in[3];
    const float* bias  = (const float*)d_in[4];
    const float* temb  = (const float*)d_in[5];

    float* out       = (float*)d_out;
    float* out_tape  = out;                                // 262144
    float* out_valid = out + (size_t)B_ * E_ * D_;         // 256
    float* out_times = out_valid + B_ * E_;                // 256

    // ws layout: [0] times (256 int) | [1KB] valid (256 int)
    int* ws_times = (int*)d_ws;
    int* ws_valid = (int*)((char*)d_ws + 1024);

    k_select<<<B_, 1024, 0, stream>>>(z, ws_times, ws_valid,
                                      out_valid, out_times);

    k_gemm<<<256, 256, 0, stream>>>(h_seq, ent, W, bias, temb,
                                    ws_times, ws_valid, out_tape);
}